// Round 8
// baseline (87.371 us; speedup 1.0000x reference)
//
#include <hip/hip_runtime.h>
#include <hip/hip_bf16.h>

#define M_DIM 4096
#define N_DIM 16384
#define K_DIM 256

typedef short short8 __attribute__((ext_vector_type(8)));
typedef float f32x4 __attribute__((ext_vector_type(4)));
typedef unsigned int u32x4 __attribute__((ext_vector_type(4)));

// fp32 -> bf16 (RNE) pack of two floats into one u32 (lo = first elem)
__device__ __forceinline__ unsigned int pk2bf(float lo, float hi) {
    unsigned int a = __float_as_uint(lo);
    unsigned int b = __float_as_uint(hi);
    a = (a + 0x7FFFu + ((a >> 16) & 1u)) >> 16;
    b = (b + 0x7FFFu + ((b >> 16) & 1u)) & 0xFFFF0000u;
    return a | b;
}

// ---------------------------------------------------------------------------
// Pre-pass (R7 version, ~5 us): one launch, 1024 blocks.
//   blocks [0,512):    W [K][N] f32 -> Wt [N][K] bf16 (mask baked) via LDS
//                      transpose; reads coalesced in n, writes full lines in k.
//   blocks [512,1024): x [M][K] f32 -> xb bf16 flat.
// ---------------------------------------------------------------------------
__global__ __launch_bounds__(256) void convert_kernel(const float* __restrict__ W,
                                                      const float* __restrict__ x,
                                                      unsigned short* __restrict__ Wt,
                                                      unsigned short* __restrict__ xb) {
    const int bx = blockIdx.x;
    const int t  = threadIdx.x;
    if (bx < 512) {
        __shared__ unsigned short tile[128][64];   // 16 KB, XOR-swizzled rows
        const int n0  = (bx & 127) * 128;          // n-panel
        const int kc0 = (bx >> 7) * 64;            // k-chunk
        const int nn  = t & 127;                   // local n (row of tile)
        const int kh  = (t >> 7) * 32;             // k-half this thread fills
        const int jm  = (n0 + nn) >> 6;            // masked k for this n
        const int sw  = (nn & 7) << 3;             // XOR swizzle (8-elem granule)
        #pragma unroll
        for (int kk = 0; kk < 32; kk += 8) {
            float v[8];
            #pragma unroll
            for (int j = 0; j < 8; ++j) {
                const int k = kc0 + kh + kk + j;
                const float f = W[(size_t)k * N_DIM + n0 + nn];   // coalesced in n
                v[j] = (k == jm) ? 0.0f : f;
            }
            u32x4 p = { pk2bf(v[0], v[1]), pk2bf(v[2], v[3]),
                        pk2bf(v[4], v[5]), pk2bf(v[6], v[7]) };
            *(u32x4*)&tile[nn][(kh + kk) ^ sw] = p;
        }
        __syncthreads();
        const int kc = (t & 7) * 8;
        const int nr = t >> 3;
        #pragma unroll
        for (int it = 0; it < 4; ++it) {
            const int n = it * 32 + nr;
            u32x4 p = *(const u32x4*)&tile[n][kc ^ ((n & 7) << 3)];
            *(u32x4*)(Wt + (size_t)(n0 + n) * K_DIM + kc0 + kc) = p;
        }
    } else {
        const size_t base = ((size_t)(bx - 512) * 256 + t) * 8;
        float4 a = *(const float4*)(x + base);
        float4 b = *(const float4*)(x + base + 4);
        u32x4 p = { pk2bf(a.x, a.y), pk2bf(a.z, a.w),
                    pk2bf(b.x, b.y), pk2bf(b.z, b.w) };
        *(u32x4*)(xb + base) = p;
    }
}

// ---------------------------------------------------------------------------
// Main GEMM — PERSISTENT version of the R7 structure (R7 K-loop/epilogue
// verbatim). 512 blocks (2/CU); each block owns a fixed m-stripe and walks
// 8 n-tiles (same tile->XCD assignment as R7's m-fast swizzle). At kt==3 of
// gen g we issue gen g+1's global loads so they fly through the entire Cs
// epilogue -> no per-generation load-latency bubble, no launch/teardown x8,
// stores of gen g overlap compute of gen g+1.
// ---------------------------------------------------------------------------
constexpr int BM = 128, BN = 128, BK = 64;
constexpr int NGEN = 8;

__global__ __launch_bounds__(256, 2) void gemm_kernel(
        const unsigned short* __restrict__ Abf,   // [M][K] bf16
        const unsigned short* __restrict__ Bbf,   // [N][K] bf16 (masked W^T)
        const float* __restrict__ bias,           // [N] f32
        float* __restrict__ out) {                // [M][N] f32
    __shared__ __align__(16) unsigned char smem[65536];
    auto As = (unsigned short (*)[BM][BK])(smem);
    auto Bs = (unsigned short (*)[BN][BK])(smem + 32768);
    float* Cs = (float*)smem;

    // persistent schedule: block pid -> virtual tiles {pid + g*512, g=0..7}
    // under R7's sw mapping. base&31 (m) is gen-invariant; panel walks +2.
    const int pid  = blockIdx.x;                   // 0..511
    const int base = (pid & 7) * 512 + (pid >> 3);
    const int m0   = (base & 31) * BM;             // fixed per block
    int n0         = (base >> 5) * BN;             // += 2*BN per gen

    const int t    = threadIdx.x;
    const int lane = t & 63;
    const int wave = t >> 6;
    const int wm   = (wave >> 1) * 64;
    const int wn   = (wave & 1) * 64;
    const int lr   = lane & 15;
    const int lk   = (lane >> 4) * 8;

    const int srow = t >> 3;
    const int selk = (t & 7) * 8;

    const unsigned short* gA = Abf + (size_t)(m0 + srow) * K_DIM + selk;
    const unsigned short* gB = Bbf + (size_t)(n0 + srow) * K_DIM + selk;

    u32x4 ra[4], rb[4];

    auto ldreg = [&](int kt) {
        #pragma unroll
        for (int r = 0; r < 4; ++r) {
            ra[r] = *(const u32x4*)(gA + (size_t)(r * 32) * K_DIM + kt * BK);
            rb[r] = *(const u32x4*)(gB + (size_t)(r * 32) * K_DIM + kt * BK);
        }
    };
    auto dswrite = [&](int buf) {
        #pragma unroll
        for (int r = 0; r < 4; ++r) {
            const int row = srow + r * 32;
            const int c   = selk ^ ((row & 7) << 3);
            *(u32x4*)&As[buf][row][c] = ra[r];
            *(u32x4*)&Bs[buf][row][c] = rb[r];
        }
    };

    f32x4 acc[4][4];

    ldreg(0);   // gen 0, kt 0

    for (int g = 0; g < NGEN; ++g) {
        #pragma unroll
        for (int mi = 0; mi < 4; ++mi)
            #pragma unroll
            for (int ni = 0; ni < 4; ++ni)
                acc[mi][ni] = (f32x4){0.f, 0.f, 0.f, 0.f};

        dswrite(0);
        __syncthreads();

        #pragma unroll
        for (int kt = 0; kt < 4; ++kt) {
            const int buf = kt & 1;
            if (kt < 3) {
                ldreg(kt + 1);
            } else if (g < NGEN - 1) {
                gB += (size_t)2 * BN * K_DIM;   // next gen's B panel
                ldreg(0);                       // flies through the epilogue
            }
            #pragma unroll
            for (int ks = 0; ks < 2; ++ks) {
                short8 af[4], bfr[4];
                #pragma unroll
                for (int mi = 0; mi < 4; ++mi) {
                    const int row = wm + mi * 16 + lr;
                    const int c   = (ks * 32 + lk) ^ ((row & 7) << 3);
                    af[mi] = *(const short8*)&As[buf][row][c];
                }
                #pragma unroll
                for (int ni = 0; ni < 4; ++ni) {
                    const int row = wn + ni * 16 + lr;
                    const int c   = (ks * 32 + lk) ^ ((row & 7) << 3);
                    bfr[ni] = *(const short8*)&Bs[buf][row][c];
                }
                // Swapped operands: D[n][m] (verified R2): m=lane&15(+mi*16),
                // n=(lane>>4)*4+j(+ni*16)
                #pragma unroll
                for (int mi = 0; mi < 4; ++mi)
                    #pragma unroll
                    for (int ni = 0; ni < 4; ++ni)
                        acc[mi][ni] = __builtin_amdgcn_mfma_f32_16x16x32_bf16(
                            bfr[ni], af[mi], acc[mi][ni], 0, 0, 0);
            }
            if (kt < 3) {
                dswrite(buf ^ 1);
                __syncthreads();
            }
        }

        // ---- epilogue: acc -> LDS (swizzled) -> coalesced global stores ----
        __syncthreads();   // all waves done reading As/Bs before aliasing as Cs

        {
            const int rl0 = wm + lr;
            const int nl0 = wn + (lane >> 4) * 4;
            #pragma unroll
            for (int mi = 0; mi < 4; ++mi) {
                const int rl = rl0 + mi * 16;
                const int sx = (rl & 7) << 2;
                #pragma unroll
                for (int ni = 0; ni < 4; ++ni) {
                    const int nl = (nl0 + ni * 16) ^ sx;
                    *(f32x4*)&Cs[rl * BN + nl] = acc[mi][ni];
                }
            }
        }
        __syncthreads();

        {
            const int col4 = (t & 31) * 4;
            const float4 bv = *(const float4*)(bias + n0 + col4);
            #pragma unroll
            for (int p = 0; p < 16; ++p) {
                const int row = p * 8 + (t >> 5);
                const int cs  = col4 ^ ((row & 7) << 2);
                f32x4 v = *(const f32x4*)&Cs[row * BN + cs];
                v[0] += bv.x; v[1] += bv.y; v[2] += bv.z; v[3] += bv.w;
                *(f32x4*)(out + (size_t)(m0 + row) * N_DIM + n0 + col4) = v;
            }
        }

        n0 += 2 * BN;
        if (g < NGEN - 1)
            __syncthreads();   // Cs reads done before next gen's dswrite(0)
    }
}

// ---------------------------------------------------------------------------
// Fallback (only if d_ws is too small): direct fp32, slow but correct.
// ---------------------------------------------------------------------------
__global__ __launch_bounds__(256) void fallback_kernel(const float* __restrict__ x,
                                                       const float* __restrict__ W,
                                                       const float* __restrict__ bias,
                                                       float* __restrict__ out) {
    const size_t gid = (size_t)blockIdx.x * 256 + threadIdx.x;
    const size_t row = gid / (N_DIM / 8);
    const int    c0  = (int)(gid % (N_DIM / 8)) * 8;
    const int    jm  = c0 >> 6;
    float acc[8] = {0, 0, 0, 0, 0, 0, 0, 0};
    const float* xr = x + row * K_DIM;
    for (int k = 0; k < K_DIM; ++k) {
        const float xv = (k == jm) ? 0.0f : xr[k];
        const float4* wr = (const float4*)(W + (size_t)k * N_DIM + c0);
        float4 w0 = wr[0], w1 = wr[1];
        acc[0] += xv * w0.x; acc[1] += xv * w0.y;
        acc[2] += xv * w0.z; acc[3] += xv * w0.w;
        acc[4] += xv * w1.x; acc[5] += xv * w1.y;
        acc[6] += xv * w1.z; acc[7] += xv * w1.w;
    }
    float* o = out + row * N_DIM + c0;
    #pragma unroll
    for (int j = 0; j < 8; ++j) o[j] = acc[j] + bias[c0 + j];
}

// ---------------------------------------------------------------------------
extern "C" void kernel_launch(void* const* d_in, const int* in_sizes, int n_in,
                              void* d_out, int out_size, void* d_ws, size_t ws_size,
                              hipStream_t stream) {
    const float* x    = (const float*)d_in[0];   // [4096, 256]
    const float* W    = (const float*)d_in[1];   // [256, 16384]
    const float* bias = (const float*)d_in[2];   // [16384]
    float* out        = (float*)d_out;           // [4096, 16384]

    const size_t wt_bytes = (size_t)N_DIM * K_DIM * 2;   // 8 MB
    const size_t xb_bytes = (size_t)M_DIM * K_DIM * 2;   // 2 MB

    if (ws_size >= wt_bytes + xb_bytes) {
        unsigned short* Wt = (unsigned short*)d_ws;
        unsigned short* xb = (unsigned short*)((char*)d_ws + wt_bytes);

        convert_kernel<<<512 + (M_DIM * K_DIM / 8) / 256, 256, 0, stream>>>(W, x, Wt, xb);
        gemm_kernel<<<512, 256, 0, stream>>>(xb, Wt, bias, out);
    } else {
        const size_t total = (size_t)M_DIM * N_DIM / 8;
        fallback_kernel<<<(unsigned)(total / 256), 256, 0, stream>>>(x, W, bias, out);
    }
}

// Round 9
// 78.949 us; speedup vs baseline: 1.1067x; 1.1067x over previous
//
#include <hip/hip_runtime.h>
#include <hip/hip_bf16.h>

#define M_DIM 4096
#define N_DIM 16384
#define K_DIM 256

typedef short short8 __attribute__((ext_vector_type(8)));
typedef float f32x4 __attribute__((ext_vector_type(4)));
typedef unsigned int u32x4 __attribute__((ext_vector_type(4)));

// fp32 -> bf16 (RNE) pack of two floats into one u32 (lo = first elem)
__device__ __forceinline__ unsigned int pk2bf(float lo, float hi) {
    unsigned int a = __float_as_uint(lo);
    unsigned int b = __float_as_uint(hi);
    a = (a + 0x7FFFu + ((a >> 16) & 1u)) >> 16;
    b = (b + 0x7FFFu + ((b >> 16) & 1u)) & 0xFFFF0000u;
    return a | b;
}

// ---------------------------------------------------------------------------
// Pre-pass (R7 version, ~5 us): one launch, 1024 blocks.
//   blocks [0,512):    W [K][N] f32 -> Wt [N][K] bf16 (mask baked) via LDS
//                      transpose; reads coalesced in n, writes full lines in k.
//   blocks [512,1024): x [M][K] f32 -> xb bf16 flat.
// ---------------------------------------------------------------------------
__global__ __launch_bounds__(256) void convert_kernel(const float* __restrict__ W,
                                                      const float* __restrict__ x,
                                                      unsigned short* __restrict__ Wt,
                                                      unsigned short* __restrict__ xb) {
    const int bx = blockIdx.x;
    const int t  = threadIdx.x;
    if (bx < 512) {
        __shared__ unsigned short tile[128][64];   // 16 KB, XOR-swizzled rows
        const int n0  = (bx & 127) * 128;          // n-panel
        const int kc0 = (bx >> 7) * 64;            // k-chunk
        const int nn  = t & 127;                   // local n (row of tile)
        const int kh  = (t >> 7) * 32;             // k-half this thread fills
        const int jm  = (n0 + nn) >> 6;            // masked k for this n
        const int sw  = (nn & 7) << 3;             // XOR swizzle (8-elem granule)
        #pragma unroll
        for (int kk = 0; kk < 32; kk += 8) {
            float v[8];
            #pragma unroll
            for (int j = 0; j < 8; ++j) {
                const int k = kc0 + kh + kk + j;
                const float f = W[(size_t)k * N_DIM + n0 + nn];   // coalesced in n
                v[j] = (k == jm) ? 0.0f : f;
            }
            u32x4 p = { pk2bf(v[0], v[1]), pk2bf(v[2], v[3]),
                        pk2bf(v[4], v[5]), pk2bf(v[6], v[7]) };
            *(u32x4*)&tile[nn][(kh + kk) ^ sw] = p;
        }
        __syncthreads();
        const int kc = (t & 7) * 8;
        const int nr = t >> 3;
        #pragma unroll
        for (int it = 0; it < 4; ++it) {
            const int n = it * 32 + nr;
            u32x4 p = *(const u32x4*)&tile[n][kc ^ ((n & 7) << 3)];
            *(u32x4*)(Wt + (size_t)(n0 + n) * K_DIM + kc0 + kc) = p;
        }
    } else {
        const size_t base = ((size_t)(bx - 512) * 256 + t) * 8;
        float4 a = *(const float4*)(x + base);
        float4 b = *(const float4*)(x + base + 4);
        u32x4 p = { pk2bf(a.x, a.y), pk2bf(a.z, a.w),
                    pk2bf(b.x, b.y), pk2bf(b.z, b.w) };
        *(u32x4*)(xb + base) = p;
    }
}

// ---------------------------------------------------------------------------
// Main GEMM — R7 structure byte-identical EXCEPT the block->tile mapping.
// Single factor under test: n-fast-within-XCD ordering. XCD x still owns
// n-panels [16x, 16x+16) (B-band 1 MB, L2-resident, fetch unchanged vs R7),
// but consecutive blocks walk n first, then m. At any instant all XCDs sit
// on the same ~4 m-stripes x full N -> aggregate write front is contiguous
// 2 MB row-slabs (per row, 128 near-synchronized blocks assemble the full
// 64 KB) instead of R7's 512 B-chunks-at-64KB-stride column slabs, which
// concentrate on few HBM channels/pages (theory: the invariant ~82 us GEMM
// = ~55% DRAM write efficiency; fills sweeping linearly get 6.6 TB/s).
// ---------------------------------------------------------------------------
constexpr int BM = 128, BN = 128, BK = 64;

__global__ __launch_bounds__(256, 2) void gemm_kernel(
        const unsigned short* __restrict__ Abf,   // [M][K] bf16
        const unsigned short* __restrict__ Bbf,   // [N][K] bf16 (masked W^T)
        const float* __restrict__ bias,           // [N] f32
        float* __restrict__ out) {                // [M][N] f32
    __shared__ __align__(16) unsigned char smem[65536];
    auto As = (unsigned short (*)[BM][BK])(smem);
    auto Bs = (unsigned short (*)[BN][BK])(smem + 32768);
    float* Cs = (float*)smem;

    // n-fast-within-XCD mapping (the only change vs R7):
    const int bid = blockIdx.x;
    const int xcd = bid & 7;
    const int q   = bid >> 3;                  // 0..511 per XCD
    const int n0  = (xcd * 16 + (q & 15)) * BN;
    const int m0  = (q >> 4) * BM;

    const int t    = threadIdx.x;
    const int lane = t & 63;
    const int wave = t >> 6;
    const int wm   = (wave >> 1) * 64;
    const int wn   = (wave & 1) * 64;
    const int lr   = lane & 15;
    const int lk   = (lane >> 4) * 8;

    const int srow = t >> 3;
    const int selk = (t & 7) * 8;

    const unsigned short* gA = Abf + (size_t)(m0 + srow) * K_DIM + selk;
    const unsigned short* gB = Bbf + (size_t)(n0 + srow) * K_DIM + selk;

    u32x4 ra[4], rb[4];

    auto ldreg = [&](int kt) {
        #pragma unroll
        for (int r = 0; r < 4; ++r) {
            ra[r] = *(const u32x4*)(gA + (size_t)(r * 32) * K_DIM + kt * BK);
            rb[r] = *(const u32x4*)(gB + (size_t)(r * 32) * K_DIM + kt * BK);
        }
    };
    auto dswrite = [&](int buf) {
        #pragma unroll
        for (int r = 0; r < 4; ++r) {
            const int row = srow + r * 32;
            const int c   = selk ^ ((row & 7) << 3);
            *(u32x4*)&As[buf][row][c] = ra[r];
            *(u32x4*)&Bs[buf][row][c] = rb[r];
        }
    };

    f32x4 acc[4][4] = {};

    ldreg(0);
    dswrite(0);
    __syncthreads();

    #pragma unroll
    for (int kt = 0; kt < 4; ++kt) {
        const int buf = kt & 1;
        if (kt < 3) ldreg(kt + 1);
        #pragma unroll
        for (int ks = 0; ks < 2; ++ks) {
            short8 af[4], bfr[4];
            #pragma unroll
            for (int mi = 0; mi < 4; ++mi) {
                const int row = wm + mi * 16 + lr;
                const int c   = (ks * 32 + lk) ^ ((row & 7) << 3);
                af[mi] = *(const short8*)&As[buf][row][c];
            }
            #pragma unroll
            for (int ni = 0; ni < 4; ++ni) {
                const int row = wn + ni * 16 + lr;
                const int c   = (ks * 32 + lk) ^ ((row & 7) << 3);
                bfr[ni] = *(const short8*)&Bs[buf][row][c];
            }
            // Swapped operands: D[n][m] (verified R2): m=lane&15(+mi*16),
            // n=(lane>>4)*4+j(+ni*16)
            #pragma unroll
            for (int mi = 0; mi < 4; ++mi)
                #pragma unroll
                for (int ni = 0; ni < 4; ++ni)
                    acc[mi][ni] = __builtin_amdgcn_mfma_f32_16x16x32_bf16(
                        bfr[ni], af[mi], acc[mi][ni], 0, 0, 0);
        }
        if (kt < 3) {
            dswrite(buf ^ 1);
            __syncthreads();
        }
    }

    // ---- epilogue: acc -> LDS (swizzled) -> coalesced global stores ----
    __syncthreads();   // all waves done reading As/Bs before aliasing as Cs

    {
        const int rl0 = wm + lr;                  // local row for this lane
        const int nl0 = wn + (lane >> 4) * 4;     // local col (float index)
        #pragma unroll
        for (int mi = 0; mi < 4; ++mi) {
            const int rl = rl0 + mi * 16;
            const int sx = (rl & 7) << 2;         // XOR swizzle, 4-float granule
            #pragma unroll
            for (int ni = 0; ni < 4; ++ni) {
                const int nl = (nl0 + ni * 16) ^ sx;
                *(f32x4*)&Cs[rl * BN + nl] = acc[mi][ni];
            }
        }
    }
    __syncthreads();

    {
        const int col4 = (t & 31) * 4;            // float col, 0..124
        const float4 bv = *(const float4*)(bias + n0 + col4);
        #pragma unroll
        for (int p = 0; p < 16; ++p) {
            const int row = p * 8 + (t >> 5);
            const int cs  = col4 ^ ((row & 7) << 2);
            f32x4 v = *(const f32x4*)&Cs[row * BN + cs];
            v[0] += bv.x; v[1] += bv.y; v[2] += bv.z; v[3] += bv.w;
            *(f32x4*)(out + (size_t)(m0 + row) * N_DIM + n0 + col4) = v;
        }
    }
}

// ---------------------------------------------------------------------------
// Fallback (only if d_ws is too small): direct fp32, slow but correct.
// ---------------------------------------------------------------------------
__global__ __launch_bounds__(256) void fallback_kernel(const float* __restrict__ x,
                                                       const float* __restrict__ W,
                                                       const float* __restrict__ bias,
                                                       float* __restrict__ out) {
    const size_t gid = (size_t)blockIdx.x * 256 + threadIdx.x;
    const size_t row = gid / (N_DIM / 8);
    const int    c0  = (int)(gid % (N_DIM / 8)) * 8;
    const int    jm  = c0 >> 6;
    float acc[8] = {0, 0, 0, 0, 0, 0, 0, 0};
    const float* xr = x + row * K_DIM;
    for (int k = 0; k < K_DIM; ++k) {
        const float xv = (k == jm) ? 0.0f : xr[k];
        const float4* wr = (const float4*)(W + (size_t)k * N_DIM + c0);
        float4 w0 = wr[0], w1 = wr[1];
        acc[0] += xv * w0.x; acc[1] += xv * w0.y;
        acc[2] += xv * w0.z; acc[3] += xv * w0.w;
        acc[4] += xv * w1.x; acc[5] += xv * w1.y;
        acc[6] += xv * w1.z; acc[7] += xv * w1.w;
    }
    float* o = out + row * N_DIM + c0;
    #pragma unroll
    for (int j = 0; j < 8; ++j) o[j] = acc[j] + bias[c0 + j];
}

// ---------------------------------------------------------------------------
extern "C" void kernel_launch(void* const* d_in, const int* in_sizes, int n_in,
                              void* d_out, int out_size, void* d_ws, size_t ws_size,
                              hipStream_t stream) {
    const float* x    = (const float*)d_in[0];   // [4096, 256]
    const float* W    = (const float*)d_in[1];   // [256, 16384]
    const float* bias = (const float*)d_in[2];   // [16384]
    float* out        = (float*)d_out;           // [4096, 16384]

    const size_t wt_bytes = (size_t)N_DIM * K_DIM * 2;   // 8 MB
    const size_t xb_bytes = (size_t)M_DIM * K_DIM * 2;   // 2 MB

    if (ws_size >= wt_bytes + xb_bytes) {
        unsigned short* Wt = (unsigned short*)d_ws;
        unsigned short* xb = (unsigned short*)((char*)d_ws + wt_bytes);

        convert_kernel<<<512 + (M_DIM * K_DIM / 8) / 256, 256, 0, stream>>>(W, x, Wt, xb);
        gemm_kernel<<<(M_DIM / BM) * (N_DIM / BN), 256, 0, stream>>>(xb, Wt, bias, out);
    } else {
        const size_t total = (size_t)M_DIM * N_DIM / 8;
        fallback_kernel<<<(unsigned)(total / 256), 256, 0, stream>>>(x, W, bias, out);
    }
}